// Round 9
// baseline (537.300 us; speedup 1.0000x reference)
//
#include <hip/hip_runtime.h>
#include <cstdint>
#include <cstddef>

// Problem constants
#define NB 4096
#define NL 50
#define NT 64
#define NF 3
#define NH 20
#define NO 16
#define NN (NB*NL)    // 204800 sequences
#define SB 16         // sequences per wave
#define WPB 2         // waves per block (fine-grained drain)
#define TS 16         // steps per x tile
#define HSTR 20       // hbf stride (shorts per seq) -> conflict-free pattern
#define XSTR 8        // xbf shorts per (k,seq): {xh0,xh1,xh2,bias, xl0,xl1,xl2, 0}
#define SCH (NN/64)   // 3200 sequences per sort chunk
#define FLAGV(b) (0x9E3779B9u + (unsigned)(b) * 0x85EBCA6Bu)

typedef __attribute__((ext_vector_type(8))) short bf16x8;   // 8 bf16 = 4 VGPR
typedef __attribute__((ext_vector_type(4))) float f32x4;
typedef __attribute__((ext_vector_type(2))) float f32x2;    // -> v_pk_*_f32
typedef uint2 u2a __attribute__((may_alias));
typedef uint4 u4a __attribute__((may_alias));

#define MFMA(a,b,c) __builtin_amdgcn_mfma_f32_16x16x32_bf16((a),(b),(c),0,0,0)

// ---------------- fast transcendentals ----------------
#if defined(__has_builtin)
#  if __has_builtin(__builtin_amdgcn_exp2f)
#    define EXP2(x) __builtin_amdgcn_exp2f(x)
#  endif
#endif
#ifndef EXP2
extern "C" __device__ float __ocml_exp2_f32(float);
#  define EXP2(x) __ocml_exp2_f32(x)
#endif

__device__ __forceinline__ float fsig(float z) {
    return __builtin_amdgcn_rcpf(1.0f + __expf(-z));
}
__device__ __forceinline__ unsigned short f2bf(float f) {   // RNE fp32->bf16
    unsigned int x = __float_as_uint(f);
    x = (x + 0x7fffu + ((x >> 16) & 1u)) >> 16;
    return (unsigned short)x;
}
__device__ __forceinline__ float bf2f(unsigned short u) {
    return __uint_as_float(((unsigned int)u) << 16);
}
// packed RNE f32x2 -> bf16x2: D = [bf(a) | bf(b)<<16]
__device__ __forceinline__ unsigned int cvtpk(float a, float b) {
    unsigned int r;
    asm("v_cvt_pk_bf16_f32 %0, %1, %2" : "=v"(r) : "v"(a), "v"(b));
    return r;
}

// Packed 2^x on the full-rate pk-FMA pipe (trans pipe bypass).
// Magic-number split: t = RNE(x + 1.5*2^23) -> n exact in low mantissa;
// (as_uint(t) << 23) == n << 23 exactly (magic's low 9 bits are 0).
// 2^f via degree-5 Taylor of e^{f ln2} on [-0.5,0.5]: rel err < 3e-6.
// Lower clamp -120 keeps the exponent field from wrapping (poly result
// exponent 126/127 + n must stay > 0); callers guarantee x <= ~44.
__device__ __forceinline__ f32x2 exp2pk(f32x2 x) {
    const float MAG = 12582912.0f;                 // 1.5 * 2^23
    x.x = fmaxf(x.x, -120.0f);
    x.y = fmaxf(x.y, -120.0f);
    f32x2 mag2 = {MAG, MAG};
    f32x2 t = x + mag2;                            // RNE -> n
    f32x2 n = t - mag2;
    f32x2 f = x - n;                               // exact, f in [-0.5,0.5]
    f32x2 p = f * 0.0013333558f + 0.0096181291f;
    p = p * f + 0.0555041087f;
    p = p * f + 0.2402265070f;
    p = p * f + 0.6931471806f;
    p = p * f + 1.0f;
    unsigned rx = __float_as_uint(p.x) + (__float_as_uint(t.x) << 23);
    unsigned ry = __float_as_uint(p.y) + (__float_as_uint(t.y) << 23);
    return (f32x2){__uint_as_float(rx), __uint_as_float(ry)};
}

// ---------------- W fragment precompute (device body) ----------------
// wfrag K rows: 0..19 w_hh, 20..22 w_ih (B=x_hi), 23 bias (b_ih+b_hh, B=1.0),
// 24..26 w_ih again (B=x_lo), 27..31 zero. Row m <-> gate g=(m&3)*20+T*4+(m>>2).
// log2e folded: gates i,f,o scaled by -log2(e); gate g scaled by +2*log2(e).
__device__ void wfrag_body(int l,
                           const float* __restrict__ w_hh,
                           const float* __restrict__ b_ih,
                           const float* __restrict__ b_hh,
                           const float* __restrict__ w_ih,
                           unsigned int* __restrict__ wfrag)
{
    int m = l & 15, kg = l >> 4;
    for (int T = 0; T < 5; ++T) {
        int g = (m & 3) * 20 + T * 4 + (m >> 2);
        int jt = g / 20;              // 0=i 1=f 2=g 3=o
        float sc = (jt == 2) ? 2.8853900817779268f : -1.4426950408889634f;
        unsigned int hi[4], lo[4];
        for (int d = 0; d < 4; ++d) {
            unsigned int hw[2], lw[2];
            for (int e = 0; e < 2; ++e) {
                int k = kg * 8 + d * 2 + e;
                float v = 0.0f;
                if (k < 20)       v = w_hh[g * 20 + k];
                else if (k <= 22) v = w_ih[g * 3 + (k - 20)];
                else if (k == 23) v = b_ih[g] + b_hh[g];
                else if (k <= 26) v = w_ih[g * 3 + (k - 24)];
                v *= sc;
                unsigned short h16 = f2bf(v);
                float r = v - bf2f(h16);
                hw[e] = h16; lw[e] = f2bf(r);
            }
            hi[d] = hw[0] | (hw[1] << 16);
            lo[d] = lw[0] | (lw[1] << 16);
        }
        for (int d = 0; d < 4; ++d) {
            wfrag[(size_t)((T * 2 + 0) * 64 + l) * 4 + d] = hi[d];
            wfrag[(size_t)((T * 2 + 1) * 64 + l) * 4 + d] = lo[d];
        }
    }
}

// ---------------- merged sort + wfrag (single launch, 65 blocks) -----------
// Blocks 0..63: per-chunk LDS histogram -> bhist row -> release flag ->
// spin until all 64 flags set (all blocks co-resident: 65 << 256 CUs) ->
// derive bucket bases -> single-pass scatter.  Block 64: wfrag.
// Flags cleared by head_kernel each iteration; values are non-trivial
// constants so leftover workspace poison cannot satisfy the wait.
__global__ __launch_bounds__(256) void sort_kernel(
    const int* __restrict__ lengths,
    int* __restrict__ bhist,
    unsigned int* __restrict__ flags,
    int* __restrict__ order,
    int* __restrict__ len_s,
    const float* __restrict__ w_hh, const float* __restrict__ b_ih,
    const float* __restrict__ b_hh, const float* __restrict__ w_ih,
    unsigned int* __restrict__ wfrag)
{
    const int b   = blockIdx.x;
    const int tid = threadIdx.x;
    if (b == 64) {
        if (tid < 64) wfrag_body(tid, w_hh, b_ih, b_hh, w_ih, wfrag);
        return;
    }
    __shared__ int lh[64];
    __shared__ int lcnt[64];
    __shared__ int lbase[64];
    if (tid < 64) lh[tid] = 0;
    __syncthreads();
    const int base = b * SCH;
    for (int i = tid; i < SCH; i += 256) {
        int len = lengths[base + i];
        len = len < 0 ? 0 : (len > 63 ? 63 : len);
        atomicAdd(&lh[len], 1);
    }
    __syncthreads();
    if (tid < 64) bhist[b * 64 + tid] = lh[tid];
    __syncthreads();
    if (tid == 0) {
        __threadfence();   // make bhist row visible at device scope
        __hip_atomic_store(&flags[b], FLAGV(b), __ATOMIC_RELEASE,
                           __HIP_MEMORY_SCOPE_AGENT);
    }
    if (tid < 64) {
        while (__hip_atomic_load(&flags[tid], __ATOMIC_ACQUIRE,
                                 __HIP_MEMORY_SCOPE_AGENT) != FLAGV(tid)) {
            __builtin_amdgcn_s_sleep(8);
        }
    }
    __syncthreads();
    __threadfence();       // acquire: invalidate local caches before bhist reads

    if (tid < 64) {
        const int l = tid;
        int tot = 0, pre = 0;
#pragma unroll 16
        for (int bb = 0; bb < 64; ++bb) {
            int v = bhist[bb * 64 + l];
            tot += v;
            if (bb < b) pre += v;
        }
        int s = tot;                      // exclusive scan over l -> base[l]
#pragma unroll
        for (int d = 1; d < 64; d <<= 1) {
            int o = __shfl_up(s, d);
            if (l >= d) s += o;
        }
        lbase[l] = (s - tot) + pre;
        lcnt[l] = 0;
    }
    __syncthreads();
    for (int i = tid; i < SCH; i += 256) {
        int n = base + i;
        int len = lengths[n];
        len = len < 0 ? 0 : (len > 63 ? 63 : len);
        int r = atomicAdd(&lcnt[len], 1);
        int pos = lbase[len] + r;
        order[pos] = n;
        len_s[pos] = len;
    }
}

// ---------------- LSTM + summary linear (MFMA, 2 independent waves/block) ----
// Gate math: 2^x form (scales folded into weights), 5 exp + 2 rcp per
// unit-step.  24 of the 25 exps run as 12 exp2pk pairs on the full-rate
// pk-FMA pipe (trans-pipe bypass, ~10 cyc saved per pair); Ec4 stays on the
// trans pipe (odd man out).  rcp stays trans (R5: batching serializes the
// chain).  Non-trans arithmetic packed as f32x2 (R7, -6%).  h stored via
// v_cvt_pk_bf16_f32 (RNE).  Step loop split at wavemin; longest-first launch.
#define LSTM_STEP(K, MASKED)                                                     \
    {                                                                            \
        uint2 ra_ = *(const u2a*)(p1 + (K) * st1);                               \
        uint2 rb_ = *(const u2a*)(p2 + (K) * st2);                               \
        union { uint4 u; bf16x8 v; } bb_;                                        \
        bb_.u = make_uint4(ra_.x, ra_.y, rb_.x, rb_.y);                          \
        f32x4 acc0, acc1, acc2, acc3, acc4;                                      \
        { f32x4 z4 = {0.f,0.f,0.f,0.f};                                          \
          z4 = MFMA(wf[0], bb_.v, z4); acc0 = MFMA(wf[1], bb_.v, z4); }          \
        { f32x4 z4 = {0.f,0.f,0.f,0.f};                                          \
          z4 = MFMA(wf[2], bb_.v, z4); acc1 = MFMA(wf[3], bb_.v, z4); }          \
        { f32x4 z4 = {0.f,0.f,0.f,0.f};                                          \
          z4 = MFMA(wf[4], bb_.v, z4); acc2 = MFMA(wf[5], bb_.v, z4); }          \
        { f32x4 z4 = {0.f,0.f,0.f,0.f};                                          \
          z4 = MFMA(wf[6], bb_.v, z4); acc3 = MFMA(wf[7], bb_.v, z4); }          \
        { f32x4 z4 = {0.f,0.f,0.f,0.f};                                          \
          z4 = MFMA(wf[8], bb_.v, z4); acc4 = MFMA(wf[9], bb_.v, z4); }          \
        bool m_ = true;                                                          \
        if (MASKED) m_ = (t0 + (K)) < mylen;                                     \
        f32x2 EiA = exp2pk((f32x2){acc0[0], acc1[0]});                           \
        f32x2 EfA = exp2pk((f32x2){acc0[1], acc1[1]});                           \
        f32x2 GA  = exp2pk((f32x2){acc0[2], acc1[2]});                           \
        f32x2 EoA = exp2pk((f32x2){acc0[3], acc1[3]});                           \
        f32x2 EiB = exp2pk((f32x2){acc2[0], acc3[0]});                           \
        f32x2 EfB = exp2pk((f32x2){acc2[1], acc3[1]});                           \
        f32x2 GB  = exp2pk((f32x2){acc2[2], acc3[2]});                           \
        f32x2 EoB = exp2pk((f32x2){acc2[3], acc3[3]});                           \
        f32x2 t1A = (1.0f + EiA) * (1.0f + GA);                                  \
        f32x2 t1B = (1.0f + EiB) * (1.0f + GB);                                  \
        f32x2 AfA = 1.0f + EfA, AfB = 1.0f + EfB;                                \
        f32x2 numA = (GA - 1.0f) * AfA + cA * t1A;                               \
        f32x2 numB = (GB - 1.0f) * AfB + cB * t1B;                               \
        f32x2 dA = t1A * AfA, dB = t1B * AfB;                                    \
        f32x2 cnA, cnB;                                                          \
        cnA.x = numA.x * __builtin_amdgcn_rcpf(dA.x);                            \
        cnA.y = numA.y * __builtin_amdgcn_rcpf(dA.y);                            \
        cnB.x = numB.x * __builtin_amdgcn_rcpf(dB.x);                            \
        cnB.y = numB.y * __builtin_amdgcn_rcpf(dB.y);                            \
        f32x2 ceA = cnA * 2.8853900817779268f;                                   \
        f32x2 ceB = cnB * 2.8853900817779268f;                                   \
        ceA.x = fminf(ceA.x, 43.3f); ceA.y = fminf(ceA.y, 43.3f);                \
        ceB.x = fminf(ceB.x, 43.3f); ceB.y = fminf(ceB.y, 43.3f);                \
        f32x2 EcA = exp2pk(ceA);                                                 \
        f32x2 EcB = exp2pk(ceB);                                                 \
        f32x2 e2A = (1.0f + EoA) * (1.0f + EcA);                                 \
        f32x2 e2B = (1.0f + EoB) * (1.0f + EcB);                                 \
        f32x2 emA = EcA - 1.0f, emB = EcB - 1.0f;                                \
        f32x2 hnA, hnB;                                                          \
        hnA.x = emA.x * __builtin_amdgcn_rcpf(e2A.x);                            \
        hnA.y = emA.y * __builtin_amdgcn_rcpf(e2A.y);                            \
        hnB.x = emB.x * __builtin_amdgcn_rcpf(e2B.x);                            \
        hnB.y = emB.y * __builtin_amdgcn_rcpf(e2B.y);                            \
        f32x2 u4a_ = exp2pk((f32x2){acc4[0], acc4[1]});  /* Ei4, Ef4 */          \
        f32x2 u4b_ = exp2pk((f32x2){acc4[2], acc4[3]});  /* G4,  Eo4 */          \
        float Ei4 = u4a_.x, Ef4 = u4a_.y;                                        \
        float G4 = u4b_.x, Eo4 = u4b_.y;                                         \
        float t14 = (1.0f + Ei4) * (1.0f + G4);                                  \
        float Af4 = 1.0f + Ef4;                                                  \
        float num4 = fmaf(G4 - 1.0f, Af4, c4s * t14);                            \
        float cn4 = num4 * __builtin_amdgcn_rcpf(t14 * Af4);                     \
        float Ec4 = EXP2(fminf(cn4 * 2.8853900817779268f, 43.3f));               \
        float hn4 = (Ec4 - 1.0f) *                                               \
                    __builtin_amdgcn_rcpf((1.0f + Eo4) * (1.0f + Ec4));          \
        unsigned int h0_ = cvtpk(hnA.x, hnA.x);                                  \
        unsigned int h1_ = cvtpk(hnA.y, hnA.y);                                  \
        unsigned int h2_ = cvtpk(hnB.x, hnB.x);                                  \
        unsigned int h3_ = cvtpk(hnB.y, hnB.y);                                  \
        unsigned int h4_ = cvtpk(hn4, hn4);                                      \
        if (m_) {                                                                \
            cA = cnA; cB = cnB; c4s = cn4;                                       \
            hbf[wid][hoff +  0] = (unsigned short)h0_;                           \
            hbf[wid][hoff +  4] = (unsigned short)h1_;                           \
            hbf[wid][hoff +  8] = (unsigned short)h2_;                           \
            hbf[wid][hoff + 12] = (unsigned short)h3_;                           \
            hbf[wid][hoff + 16] = (unsigned short)h4_;                           \
        }                                                                        \
    }

__global__ __launch_bounds__(128) void lstm_kernel(
    const float* __restrict__ x,        // [NN][64][3]
    const int*   __restrict__ len_s,    // [NN] sorted lengths
    const int*   __restrict__ order,    // [NN] sorted indices
    const unsigned int* __restrict__ wfrag, // [10][64][4]
    const float* __restrict__ w_lin,    // [16][20]
    const float* __restrict__ b_lin,    // [16]
    float* __restrict__ feat)           // [NN][16]
{
    __shared__ __align__(16) unsigned short hbf[WPB][SB * HSTR];       // 1.25 KB
    __shared__ __align__(16) unsigned short xbf[WPB][TS * SB * XSTR];  // 8 KB
    __shared__ __align__(16) unsigned short zbuf[WPB][8];              // 32 B

    const int tid  = threadIdx.x;
    const int wid  = __builtin_amdgcn_readfirstlane(tid >> 6);
    const int lane = tid & 63;
    const int n16  = lane & 15;
    const int kg   = lane >> 4;
    // reverse order: longest-length segments launch first (tail balance)
    const int base = ((gridDim.x - 1 - blockIdx.x) * WPB + wid) * SB;

    const int mylen   = len_s[base + n16];
    const int wavemin = len_s[base];             // ascending sort
    const int wavemax = len_s[base + SB - 1];

    // per-wave LDS init (no cross-wave deps -> no barrier)
    for (int i = lane; i < SB * HSTR; i += 64) hbf[wid][i] = 0;
    if (lane < 8) zbuf[wid][lane] = 0;

    // x gather map: lane = (seq ssl)<<2 | t-quarter tq; each lane owns 4
    // complete (t,seq) cells = 12 consecutive floats = 3 aligned float4.
    int nown = order[base + n16];
    const int ssl = lane >> 2;
    const int tq  = lane & 3;
    int nsl = __shfl(nown, ssl);
    const size_t gbase = (size_t)nsl * (NT * NF) + (size_t)tq * 12;  // floats

    // step-loop LDS addressing: frag = [p1: rows 8kg..8kg+3][p2: rows +4..+7]
    const unsigned short* hpw = &hbf[wid][n16 * HSTR];
    const unsigned short* p1 = (kg < 3) ? (hpw + kg * 8)
                                        : &xbf[wid][n16 * XSTR + 4];
    const unsigned short* p2 = (kg < 2) ? (hpw + kg * 8 + 4)
                             : (kg == 2 ? &xbf[wid][n16 * XSTR]
                                        : &zbuf[wid][0]);
    const int st1 = (kg == 3) ? SB * XSTR : 0;   // shorts per step
    const int st2 = (kg == 2) ? SB * XSTR : 0;
    const int hoff = n16 * HSTR + kg;

    if (wavemax > 0) {
        // W fragments: 5 tiles x {hi,lo}
        bf16x8 wf[10];
#pragma unroll
        for (int p = 0; p < 10; ++p) {
            union { uint4 i; bf16x8 v; } cv;
            cv.i = ((const uint4*)wfrag)[p * 64 + lane];
            wf[p] = cv.v;
        }

        f32x2 cA = {0.f, 0.f}, cB = {0.f, 0.f};
        float c4s = 0.f;

        float4 vf[3];
#pragma unroll
        for (int j = 0; j < 3; ++j) vf[j] = *(const float4*)(x + gbase + 4 * j);

        for (int t0 = 0; t0 < wavemax; t0 += TS) {
            // stage tile: 4 cells/lane, one ds_write_b128 per cell
            float f12[12] = {vf[0].x, vf[0].y, vf[0].z, vf[0].w,
                             vf[1].x, vf[1].y, vf[1].z, vf[1].w,
                             vf[2].x, vf[2].y, vf[2].z, vf[2].w};
#pragma unroll
            for (int jj = 0; jj < 4; ++jj) {
                float a0 = f12[3 * jj], a1 = f12[3 * jj + 1], a2 = f12[3 * jj + 2];
                unsigned int w0 = cvtpk(a0, a1);          // [xh0|xh1]
                unsigned int w1 = cvtpk(a2, 1.0f);        // [xh2|bias]
                float r0 = a0 - __uint_as_float(w0 << 16);
                float r1 = a1 - __uint_as_float(w0 & 0xFFFF0000u);
                float r2 = a2 - __uint_as_float(w1 << 16);
                unsigned int w2 = cvtpk(r0, r1);          // [xl0|xl1]
                unsigned int w3 = cvtpk(r2, 0.0f);        // [xl2|0]
                int t = tq * 4 + jj;
                *(u4a*)&xbf[wid][(t * SB + ssl) * XSTR] = make_uint4(w0, w1, w2, w3);
            }
            // prefetch next tile
            if (t0 + TS < wavemax) {
                size_t off = (size_t)(t0 + TS) * NF;
#pragma unroll
                for (int j = 0; j < 3; ++j)
                    vf[j] = *(const float4*)(x + gbase + off + 4 * j);
            }

            int kmax = wavemax - t0; if (kmax > TS) kmax = TS;
            int ku = wavemin - t0;
            ku = ku < 0 ? 0 : (ku > kmax ? kmax : ku);
            int k = 0;
            for (; k < ku; ++k)   LSTM_STEP(k, false)   // all lanes active
            for (; k < kmax; ++k) LSTM_STEP(k, true)    // masked tail
        }
    }

    // epilogue: summary linear. Lane (n16,kg) -> outputs o = 4*kg..4*kg+3
    float hl[NH];
#pragma unroll
    for (int u = 0; u < NH; ++u) hl[u] = bf2f(hbf[wid][n16 * HSTR + u]);
    float4 res;
    if (mylen > 0) {
        float r4[4];
#pragma unroll
        for (int j = 0; j < 4; ++j) {
            int o = 4 * kg + j;
            float aa = b_lin[o];
#pragma unroll
            for (int kk = 0; kk < NH; ++kk) aa += w_lin[o * NH + kk] * hl[kk];
            r4[j] = fsig(aa);
        }
        res = make_float4(r4[0], r4[1], r4[2], r4[3]);
    } else {
        res = make_float4(0.f, 0.f, 0.f, 0.f);
    }
    *(float4*)(feat + (size_t)nown * NO + 4 * kg) = res;
}

// ---------------- conv stack + fc head: 2 batch rows per block ----
// LDS arena with lifetime overlay ({sf|y1} peak 18.2 KB -> 8 blocks/CU).
// Conv accumulators packed as f32x2 pairs over oc -> v_pk_fma_f32 (R7 idiom).
// Wave q handles oc q*8..q*8+7; conv2/conv3 put batch 0 on lanes 0..31 and
// batch 1 on lanes 32..63.  fc1/fc2 run on waves 0 and 1.
// Block 0 clears the sort barrier flags for the next iteration.
__global__ __launch_bounds__(256) void head_kernel(
    const float* __restrict__ feat,  // [NB][NL][16]
    unsigned int* __restrict__ flags,
    const float* __restrict__ c1w, const float* __restrict__ c1b,
    const float* __restrict__ c2w, const float* __restrict__ c2b,
    const float* __restrict__ c3w, const float* __restrict__ c3b,
    const float* __restrict__ f1w, const float* __restrict__ f1b,
    const float* __restrict__ f2w, const float* __restrict__ f2b,
    float* __restrict__ out)         // [NB][4]
{
    const int b0  = blockIdx.x * 2;
    const int tid = threadIdx.x;
    const int p   = tid & 63;
    const int q   = __builtin_amdgcn_readfirstlane(tid >> 6);  // oc-octet 0..3
    const int half = p >> 5;         // batch within wave (conv2/3)
    const int pp   = p & 31;         // position within half

    if (blockIdx.x == 0 && tid < 64) flags[tid] = 0u;  // reset sort barrier

    // arena (floats): [0,1600) sf -> later y2 [0,1408) + r1 [1440,1472)
    //                 [1600,4544) y1 -> later y3 [1600,2816)
    __shared__ __align__(16) float arena[4544];        // 18176 B
    float* sfp = arena;              // sf[bb][o*50+l]   = sfp[bb*800 + ...]
    float* y1p = arena + 1600;       // y1[bb][oc*46+p]  = y1p[bb*1472 + ...]
    float* y2p = arena;              // y2[bb][oc*22+pp] = y2p[bb*704 + ...]
    float* y3p = arena + 1600;       // y3[bb][oc*19+pp] = y3p[bb*608 + ...]
    float* r1p = arena + 1440;       // r1[bb][u]        = r1p[bb*16 + u]

    for (int i = tid; i < 2 * NL * NO; i += 256) {
        int bb = (i >= NL * NO) ? 1 : 0;
        int j = i - bb * (NL * NO);
        int l = j >> 4, o = j & 15;
        sfp[bb * 800 + o * 50 + l] = feat[(size_t)(b0 + bb) * (NL * NO) + j];
    }
    __syncthreads();

    const int oc0 = q * 8;

    // conv1: 16ch k5 s1 -> 32ch x 46, relu. Two passes (one per batch);
    // weights are wave-uniform and hoisted across passes.
#pragma unroll
    for (int bb = 0; bb < 2; ++bb) {
        if (p < 46) {
            f32x2 acc[4];
#pragma unroll
            for (int j = 0; j < 4; ++j)
                acc[j] = (f32x2){c1b[oc0 + 2*j], c1b[oc0 + 2*j + 1]};
#pragma unroll
            for (int ic = 0; ic < 16; ++ic) {
#pragma unroll
                for (int tap = 0; tap < 5; ++tap) {
                    float fv = sfp[bb * 800 + ic * 50 + p + tap];
                    f32x2 fv2 = {fv, fv};
#pragma unroll
                    for (int j = 0; j < 4; ++j) {
                        f32x2 w2 = {c1w[((oc0 + 2*j)     * 16 + ic) * 5 + tap],
                                    c1w[((oc0 + 2*j + 1) * 16 + ic) * 5 + tap]};
                        acc[j] += w2 * fv2;
                    }
                }
            }
#pragma unroll
            for (int j = 0; j < 4; ++j) {
                y1p[bb * 1472 + (oc0 + 2*j)     * 46 + p] = fmaxf(acc[j].x, 0.0f);
                y1p[bb * 1472 + (oc0 + 2*j + 1) * 46 + p] = fmaxf(acc[j].y, 0.0f);
            }
        }
    }
    __syncthreads();   // sf dead; y2 may overwrite it

    // conv2: 32ch k4 s2 -> 32ch x 22, relu. half = batch, pp = position.
    if (pp < 22) {
        f32x2 acc[4];
#pragma unroll
        for (int j = 0; j < 4; ++j)
            acc[j] = (f32x2){c2b[oc0 + 2*j], c2b[oc0 + 2*j + 1]};
#pragma unroll
        for (int ic = 0; ic < 32; ++ic) {
#pragma unroll
            for (int tap = 0; tap < 4; ++tap) {
                float fv = y1p[half * 1472 + ic * 46 + 2 * pp + tap];
                f32x2 fv2 = {fv, fv};
#pragma unroll
                for (int j = 0; j < 4; ++j) {
                    f32x2 w2 = {c2w[((oc0 + 2*j)     * 32 + ic) * 4 + tap],
                                c2w[((oc0 + 2*j + 1) * 32 + ic) * 4 + tap]};
                    acc[j] += w2 * fv2;
                }
            }
        }
#pragma unroll
        for (int j = 0; j < 4; ++j) {
            y2p[half * 704 + (oc0 + 2*j)     * 22 + pp] = fmaxf(acc[j].x, 0.0f);
            y2p[half * 704 + (oc0 + 2*j + 1) * 22 + pp] = fmaxf(acc[j].y, 0.0f);
        }
    }
    __syncthreads();   // y1 dead; y3 may overwrite it

    // conv3: 32ch k4 s1 -> 32ch x 19, relu
    if (pp < 19) {
        f32x2 acc[4];
#pragma unroll
        for (int j = 0; j < 4; ++j)
            acc[j] = (f32x2){c3b[oc0 + 2*j], c3b[oc0 + 2*j + 1]};
#pragma unroll
        for (int ic = 0; ic < 32; ++ic) {
#pragma unroll
            for (int tap = 0; tap < 4; ++tap) {
                float fv = y2p[half * 704 + ic * 22 + pp + tap];
                f32x2 fv2 = {fv, fv};
#pragma unroll
                for (int j = 0; j < 4; ++j) {
                    f32x2 w2 = {c3w[((oc0 + 2*j)     * 32 + ic) * 4 + tap],
                                c3w[((oc0 + 2*j + 1) * 32 + ic) * 4 + tap]};
                    acc[j] += w2 * fv2;
                }
            }
        }
#pragma unroll
        for (int j = 0; j < 4; ++j) {
            y3p[half * 608 + (oc0 + 2*j)     * 19 + pp] = fmaxf(acc[j].x, 0.0f);
            y3p[half * 608 + (oc0 + 2*j + 1) * 19 + pp] = fmaxf(acc[j].y, 0.0f);
        }
    }
    __syncthreads();

    // fc1: 608 -> 16, relu. Wave 0 -> batch 0, wave 1 -> batch 1.
    // float4 weight loads + same-address (broadcast) float4 LDS reads.
    if (q < 2) {
        int u  = p & 15;
        int qq = p >> 4;
        const float4* wv = (const float4*)(f1w + u * 608 + qq * 152);
        const float4* yv = (const float4*)(y3p + q * 608 + qq * 152);
        float acc = 0.0f;
#pragma unroll 2
        for (int k = 0; k < 38; ++k) {
            float4 a = wv[k], bv = yv[k];
            acc += a.x * bv.x + a.y * bv.y + a.z * bv.z + a.w * bv.w;
        }
        acc += __shfl_xor(acc, 16);
        acc += __shfl_xor(acc, 32);
        if (p < 16) r1p[q * 16 + p] = fmaxf(acc + f1b[p], 0.0f);
    }
    __syncthreads();

    // fc2: 16 -> 4. Wave 0 -> batch 0, wave 1 -> batch 1.
    if (q < 2 && p < 4) {
        float s = f2b[p];
#pragma unroll
        for (int k = 0; k < 16; ++k) s += f2w[p * 16 + k] * r1p[q * 16 + k];
        out[(size_t)(b0 + q) * 4 + p] = s;
    }
}

extern "C" void kernel_launch(void* const* d_in, const int* in_sizes, int n_in,
                              void* d_out, int out_size, void* d_ws, size_t ws_size,
                              hipStream_t stream)
{
    const float* x     = (const float*)d_in[0];
    const int*  lengths= (const int*)  d_in[1];
    const float* w_ih  = (const float*)d_in[2];
    const float* w_hh  = (const float*)d_in[3];
    const float* b_ih  = (const float*)d_in[4];
    const float* b_hh  = (const float*)d_in[5];
    const float* w_lin = (const float*)d_in[6];
    const float* b_lin = (const float*)d_in[7];
    const float* c1w   = (const float*)d_in[8];
    const float* c1b   = (const float*)d_in[9];
    const float* c2w   = (const float*)d_in[10];
    const float* c2b   = (const float*)d_in[11];
    const float* c3w   = (const float*)d_in[12];
    const float* c3b   = (const float*)d_in[13];
    const float* f1w   = (const float*)d_in[14];
    const float* f1b   = (const float*)d_in[15];
    const float* f2w   = (const float*)d_in[16];
    const float* f2b   = (const float*)d_in[17];
    float* out = (float*)d_out;

    // workspace layout (~14.8 MB), all segments 16B-aligned
    char* ws      = (char*)d_ws;
    float* feat   = (float*)ws;                       // NN*16 floats
    int*   order  = (int*)(feat + (size_t)NN * NO);   // NN
    int*   len_s  = order + NN;                       // NN
    int*   bhist  = len_s + NN;                       // 64*64
    unsigned int* flags = (unsigned int*)(bhist + 64 * 64); // 64
    unsigned int* wfrag = flags + 64;                 // 2560

    sort_kernel <<<65, 256, 0, stream>>>(lengths, bhist, flags, order, len_s,
                                         w_hh, b_ih, b_hh, w_ih, wfrag);
    lstm_kernel <<<NN / (SB * WPB), 128, 0, stream>>>(x, len_s, order, wfrag,
                                                      w_lin, b_lin, feat);
    head_kernel <<<NB / 2, 256, 0, stream>>>(feat, flags,
                                             c1w, c1b, c2w, c2b, c3w, c3b,
                                             f1w, f1b, f2w, f2b, out);
}

// Round 10
// 453.292 us; speedup vs baseline: 1.1853x; 1.1853x over previous
//
#include <hip/hip_runtime.h>
#include <cstdint>
#include <cstddef>

// Problem constants
#define NB 4096
#define NL 50
#define NT 64
#define NF 3
#define NH 20
#define NO 16
#define NN (NB*NL)    // 204800 sequences
#define SB 16         // sequences per wave
#define WPB 2         // waves per block (fine-grained drain)
#define TS 16         // steps per x tile
#define HSTR 20       // hbf stride (shorts per seq) -> conflict-free pattern
#define XSTR 8        // xbf shorts per (k,seq): {xh0,xh1,xh2,bias, xl0,xl1,xl2, 0}
#define SCH (NN/64)   // 3200 sequences per sort chunk
#define FLAGV(b) (0x9E3779B9u + (unsigned)(b) * 0x85EBCA6Bu)

typedef __attribute__((ext_vector_type(8))) short bf16x8;   // 8 bf16 = 4 VGPR
typedef __attribute__((ext_vector_type(4))) float f32x4;
typedef __attribute__((ext_vector_type(2))) float f32x2;    // -> v_pk_*_f32
typedef uint2 u2a __attribute__((may_alias));
typedef uint4 u4a __attribute__((may_alias));

#define MFMA(a,b,c) __builtin_amdgcn_mfma_f32_16x16x32_bf16((a),(b),(c),0,0,0)

// ---------------- fast transcendentals ----------------
// NOTE (R9 lesson): v_exp_f32 runs on the TRANS pipe, which executes
// CONCURRENTLY with the VALU pipe.  The 25 exps/step are largely hidden
// under packed-VALU issue; replacing them with polynomial pk-FMA chains
// (R9) moved ~500 dependent cycles/step onto the binding VALU port and
// regressed 152->255 us.  Keep exps on the trans pipe.
#if defined(__has_builtin)
#  if __has_builtin(__builtin_amdgcn_exp2f)
#    define EXP2(x) __builtin_amdgcn_exp2f(x)
#  endif
#endif
#ifndef EXP2
extern "C" __device__ float __ocml_exp2_f32(float);
#  define EXP2(x) __ocml_exp2_f32(x)
#endif

__device__ __forceinline__ float fsig(float z) {
    return __builtin_amdgcn_rcpf(1.0f + __expf(-z));
}
__device__ __forceinline__ unsigned short f2bf(float f) {   // RNE fp32->bf16
    unsigned int x = __float_as_uint(f);
    x = (x + 0x7fffu + ((x >> 16) & 1u)) >> 16;
    return (unsigned short)x;
}
__device__ __forceinline__ float bf2f(unsigned short u) {
    return __uint_as_float(((unsigned int)u) << 16);
}
// packed RNE f32x2 -> bf16x2: D = [bf(a) | bf(b)<<16]
__device__ __forceinline__ unsigned int cvtpk(float a, float b) {
    unsigned int r;
    asm("v_cvt_pk_bf16_f32 %0, %1, %2" : "=v"(r) : "v"(a), "v"(b));
    return r;
}

// ---------------- W fragment precompute (device body) ----------------
// wfrag K rows: 0..19 w_hh, 20..22 w_ih (B=x_hi), 23 bias (b_ih+b_hh, B=1.0),
// 24..26 w_ih again (B=x_lo), 27..31 zero. Row m <-> gate g=(m&3)*20+T*4+(m>>2).
// log2e folded: gates i,f,o scaled by -log2(e); gate g scaled by +2*log2(e).
__device__ void wfrag_body(int l,
                           const float* __restrict__ w_hh,
                           const float* __restrict__ b_ih,
                           const float* __restrict__ b_hh,
                           const float* __restrict__ w_ih,
                           unsigned int* __restrict__ wfrag)
{
    int m = l & 15, kg = l >> 4;
    for (int T = 0; T < 5; ++T) {
        int g = (m & 3) * 20 + T * 4 + (m >> 2);
        int jt = g / 20;              // 0=i 1=f 2=g 3=o
        float sc = (jt == 2) ? 2.8853900817779268f : -1.4426950408889634f;
        unsigned int hi[4], lo[4];
        for (int d = 0; d < 4; ++d) {
            unsigned int hw[2], lw[2];
            for (int e = 0; e < 2; ++e) {
                int k = kg * 8 + d * 2 + e;
                float v = 0.0f;
                if (k < 20)       v = w_hh[g * 20 + k];
                else if (k <= 22) v = w_ih[g * 3 + (k - 20)];
                else if (k == 23) v = b_ih[g] + b_hh[g];
                else if (k <= 26) v = w_ih[g * 3 + (k - 24)];
                v *= sc;
                unsigned short h16 = f2bf(v);
                float r = v - bf2f(h16);
                hw[e] = h16; lw[e] = f2bf(r);
            }
            hi[d] = hw[0] | (hw[1] << 16);
            lo[d] = lw[0] | (lw[1] << 16);
        }
        for (int d = 0; d < 4; ++d) {
            wfrag[(size_t)((T * 2 + 0) * 64 + l) * 4 + d] = hi[d];
            wfrag[(size_t)((T * 2 + 1) * 64 + l) * 4 + d] = lo[d];
        }
    }
}

// ---------------- merged sort + wfrag (single launch, 65 blocks) -----------
// Blocks 0..63: per-chunk LDS histogram -> bhist row -> release flag ->
// spin until all 64 flags set (all blocks co-resident: 65 << 256 CUs) ->
// derive bucket bases -> single-pass scatter.  Block 64: wfrag.
// Flags cleared by head_kernel each iteration; values are non-trivial
// constants so leftover workspace poison cannot satisfy the wait.
__global__ __launch_bounds__(256) void sort_kernel(
    const int* __restrict__ lengths,
    int* __restrict__ bhist,
    unsigned int* __restrict__ flags,
    int* __restrict__ order,
    int* __restrict__ len_s,
    const float* __restrict__ w_hh, const float* __restrict__ b_ih,
    const float* __restrict__ b_hh, const float* __restrict__ w_ih,
    unsigned int* __restrict__ wfrag)
{
    const int b   = blockIdx.x;
    const int tid = threadIdx.x;
    if (b == 64) {
        if (tid < 64) wfrag_body(tid, w_hh, b_ih, b_hh, w_ih, wfrag);
        return;
    }
    __shared__ int lh[64];
    __shared__ int lcnt[64];
    __shared__ int lbase[64];
    if (tid < 64) lh[tid] = 0;
    __syncthreads();
    const int base = b * SCH;
    for (int i = tid; i < SCH; i += 256) {
        int len = lengths[base + i];
        len = len < 0 ? 0 : (len > 63 ? 63 : len);
        atomicAdd(&lh[len], 1);
    }
    __syncthreads();
    if (tid < 64) bhist[b * 64 + tid] = lh[tid];
    __syncthreads();
    if (tid == 0) {
        __threadfence();   // make bhist row visible at device scope
        __hip_atomic_store(&flags[b], FLAGV(b), __ATOMIC_RELEASE,
                           __HIP_MEMORY_SCOPE_AGENT);
    }
    if (tid < 64) {
        while (__hip_atomic_load(&flags[tid], __ATOMIC_ACQUIRE,
                                 __HIP_MEMORY_SCOPE_AGENT) != FLAGV(tid)) {
            __builtin_amdgcn_s_sleep(8);
        }
    }
    __syncthreads();
    __threadfence();       // acquire: invalidate local caches before bhist reads

    if (tid < 64) {
        const int l = tid;
        int tot = 0, pre = 0;
#pragma unroll 16
        for (int bb = 0; bb < 64; ++bb) {
            int v = bhist[bb * 64 + l];
            tot += v;
            if (bb < b) pre += v;
        }
        int s = tot;                      // exclusive scan over l -> base[l]
#pragma unroll
        for (int d = 1; d < 64; d <<= 1) {
            int o = __shfl_up(s, d);
            if (l >= d) s += o;
        }
        lbase[l] = (s - tot) + pre;
        lcnt[l] = 0;
    }
    __syncthreads();
    for (int i = tid; i < SCH; i += 256) {
        int n = base + i;
        int len = lengths[n];
        len = len < 0 ? 0 : (len > 63 ? 63 : len);
        int r = atomicAdd(&lcnt[len], 1);
        int pos = lbase[len] + r;
        order[pos] = n;
        len_s[pos] = len;
    }
}

// ---------------- LSTM + summary linear (MFMA, 2 independent waves/block) ----
// Gate math: 2^x form (scales folded into weights), 5 exp + 2 rcp per
// unit-step.  The 5 units are processed as two f32x2 PAIRS + 1 scalar so the
// ~28 add/mul/fma per pair lower to v_pk_{add,mul,fma}_f32 (CDNA packed
// FP32, full rate) -- halves the non-trans VALU issue.  exp/rcp stay on the
// trans pipe (concurrent with VALU; R9 showed polynomial replacement
// regresses 67%).  h stored via v_cvt_pk_bf16_f32 (RNE).
// Step loop split at wavemin; blocks launched longest-first.
#define LSTM_STEP(K, MASKED)                                                     \
    {                                                                            \
        uint2 ra_ = *(const u2a*)(p1 + (K) * st1);                               \
        uint2 rb_ = *(const u2a*)(p2 + (K) * st2);                               \
        union { uint4 u; bf16x8 v; } bb_;                                        \
        bb_.u = make_uint4(ra_.x, ra_.y, rb_.x, rb_.y);                          \
        f32x4 acc0, acc1, acc2, acc3, acc4;                                      \
        { f32x4 z4 = {0.f,0.f,0.f,0.f};                                          \
          z4 = MFMA(wf[0], bb_.v, z4); acc0 = MFMA(wf[1], bb_.v, z4); }          \
        { f32x4 z4 = {0.f,0.f,0.f,0.f};                                          \
          z4 = MFMA(wf[2], bb_.v, z4); acc1 = MFMA(wf[3], bb_.v, z4); }          \
        { f32x4 z4 = {0.f,0.f,0.f,0.f};                                          \
          z4 = MFMA(wf[4], bb_.v, z4); acc2 = MFMA(wf[5], bb_.v, z4); }          \
        { f32x4 z4 = {0.f,0.f,0.f,0.f};                                          \
          z4 = MFMA(wf[6], bb_.v, z4); acc3 = MFMA(wf[7], bb_.v, z4); }          \
        { f32x4 z4 = {0.f,0.f,0.f,0.f};                                          \
          z4 = MFMA(wf[8], bb_.v, z4); acc4 = MFMA(wf[9], bb_.v, z4); }          \
        bool m_ = true;                                                          \
        if (MASKED) m_ = (t0 + (K)) < mylen;                                     \
        f32x2 EiA = {EXP2(acc0[0]), EXP2(acc1[0])};                              \
        f32x2 EfA = {EXP2(acc0[1]), EXP2(acc1[1])};                              \
        f32x2 GA  = {EXP2(acc0[2]), EXP2(acc1[2])};                              \
        f32x2 EoA = {EXP2(acc0[3]), EXP2(acc1[3])};                              \
        f32x2 EiB = {EXP2(acc2[0]), EXP2(acc3[0])};                              \
        f32x2 EfB = {EXP2(acc2[1]), EXP2(acc3[1])};                              \
        f32x2 GB  = {EXP2(acc2[2]), EXP2(acc3[2])};                              \
        f32x2 EoB = {EXP2(acc2[3]), EXP2(acc3[3])};                              \
        f32x2 t1A = (1.0f + EiA) * (1.0f + GA);                                  \
        f32x2 t1B = (1.0f + EiB) * (1.0f + GB);                                  \
        f32x2 AfA = 1.0f + EfA, AfB = 1.0f + EfB;                                \
        f32x2 numA = (GA - 1.0f) * AfA + cA * t1A;                               \
        f32x2 numB = (GB - 1.0f) * AfB + cB * t1B;                               \
        f32x2 dA = t1A * AfA, dB = t1B * AfB;                                    \
        f32x2 cnA, cnB;                                                          \
        cnA.x = numA.x * __builtin_amdgcn_rcpf(dA.x);                            \
        cnA.y = numA.y * __builtin_amdgcn_rcpf(dA.y);                            \
        cnB.x = numB.x * __builtin_amdgcn_rcpf(dB.x);                            \
        cnB.y = numB.y * __builtin_amdgcn_rcpf(dB.y);                            \
        f32x2 ceA = cnA * 2.8853900817779268f;                                   \
        f32x2 ceB = cnB * 2.8853900817779268f;                                   \
        f32x2 EcA = {EXP2(fminf(ceA.x, 43.3f)), EXP2(fminf(ceA.y, 43.3f))};      \
        f32x2 EcB = {EXP2(fminf(ceB.x, 43.3f)), EXP2(fminf(ceB.y, 43.3f))};      \
        f32x2 e2A = (1.0f + EoA) * (1.0f + EcA);                                 \
        f32x2 e2B = (1.0f + EoB) * (1.0f + EcB);                                 \
        f32x2 emA = EcA - 1.0f, emB = EcB - 1.0f;                                \
        f32x2 hnA, hnB;                                                          \
        hnA.x = emA.x * __builtin_amdgcn_rcpf(e2A.x);                            \
        hnA.y = emA.y * __builtin_amdgcn_rcpf(e2A.y);                            \
        hnB.x = emB.x * __builtin_amdgcn_rcpf(e2B.x);                            \
        hnB.y = emB.y * __builtin_amdgcn_rcpf(e2B.y);                            \
        float Ei4 = EXP2(acc4[0]), Ef4 = EXP2(acc4[1]);                          \
        float G4 = EXP2(acc4[2]), Eo4 = EXP2(acc4[3]);                           \
        float t14 = (1.0f + Ei4) * (1.0f + G4);                                  \
        float Af4 = 1.0f + Ef4;                                                  \
        float num4 = fmaf(G4 - 1.0f, Af4, c4s * t14);                            \
        float cn4 = num4 * __builtin_amdgcn_rcpf(t14 * Af4);                     \
        float Ec4 = EXP2(fminf(cn4 * 2.8853900817779268f, 43.3f));               \
        float hn4 = (Ec4 - 1.0f) *                                               \
                    __builtin_amdgcn_rcpf((1.0f + Eo4) * (1.0f + Ec4));          \
        unsigned int h0_ = cvtpk(hnA.x, hnA.x);                                  \
        unsigned int h1_ = cvtpk(hnA.y, hnA.y);                                  \
        unsigned int h2_ = cvtpk(hnB.x, hnB.x);                                  \
        unsigned int h3_ = cvtpk(hnB.y, hnB.y);                                  \
        unsigned int h4_ = cvtpk(hn4, hn4);                                      \
        if (m_) {                                                                \
            cA = cnA; cB = cnB; c4s = cn4;                                       \
            hbf[wid][hoff +  0] = (unsigned short)h0_;                           \
            hbf[wid][hoff +  4] = (unsigned short)h1_;                           \
            hbf[wid][hoff +  8] = (unsigned short)h2_;                           \
            hbf[wid][hoff + 12] = (unsigned short)h3_;                           \
            hbf[wid][hoff + 16] = (unsigned short)h4_;                           \
        }                                                                        \
    }

__global__ __launch_bounds__(128) void lstm_kernel(
    const float* __restrict__ x,        // [NN][64][3]
    const int*   __restrict__ len_s,    // [NN] sorted lengths
    const int*   __restrict__ order,    // [NN] sorted indices
    const unsigned int* __restrict__ wfrag, // [10][64][4]
    const float* __restrict__ w_lin,    // [16][20]
    const float* __restrict__ b_lin,    // [16]
    float* __restrict__ feat)           // [NN][16]
{
    __shared__ __align__(16) unsigned short hbf[WPB][SB * HSTR];       // 1.25 KB
    __shared__ __align__(16) unsigned short xbf[WPB][TS * SB * XSTR];  // 8 KB
    __shared__ __align__(16) unsigned short zbuf[WPB][8];              // 32 B

    const int tid  = threadIdx.x;
    const int wid  = __builtin_amdgcn_readfirstlane(tid >> 6);
    const int lane = tid & 63;
    const int n16  = lane & 15;
    const int kg   = lane >> 4;
    // reverse order: longest-length segments launch first (tail balance)
    const int base = ((gridDim.x - 1 - blockIdx.x) * WPB + wid) * SB;

    const int mylen   = len_s[base + n16];
    const int wavemin = len_s[base];             // ascending sort
    const int wavemax = len_s[base + SB - 1];

    // per-wave LDS init (no cross-wave deps -> no barrier)
    for (int i = lane; i < SB * HSTR; i += 64) hbf[wid][i] = 0;
    if (lane < 8) zbuf[wid][lane] = 0;

    // x gather map: lane = (seq ssl)<<2 | t-quarter tq; each lane owns 4
    // complete (t,seq) cells = 12 consecutive floats = 3 aligned float4.
    int nown = order[base + n16];
    const int ssl = lane >> 2;
    const int tq  = lane & 3;
    int nsl = __shfl(nown, ssl);
    const size_t gbase = (size_t)nsl * (NT * NF) + (size_t)tq * 12;  // floats

    // step-loop LDS addressing: frag = [p1: rows 8kg..8kg+3][p2: rows +4..+7]
    const unsigned short* hpw = &hbf[wid][n16 * HSTR];
    const unsigned short* p1 = (kg < 3) ? (hpw + kg * 8)
                                        : &xbf[wid][n16 * XSTR + 4];
    const unsigned short* p2 = (kg < 2) ? (hpw + kg * 8 + 4)
                             : (kg == 2 ? &xbf[wid][n16 * XSTR]
                                        : &zbuf[wid][0]);
    const int st1 = (kg == 3) ? SB * XSTR : 0;   // shorts per step
    const int st2 = (kg == 2) ? SB * XSTR : 0;
    const int hoff = n16 * HSTR + kg;

    if (wavemax > 0) {
        // W fragments: 5 tiles x {hi,lo}
        bf16x8 wf[10];
#pragma unroll
        for (int p = 0; p < 10; ++p) {
            union { uint4 i; bf16x8 v; } cv;
            cv.i = ((const uint4*)wfrag)[p * 64 + lane];
            wf[p] = cv.v;
        }

        f32x2 cA = {0.f, 0.f}, cB = {0.f, 0.f};
        float c4s = 0.f;

        float4 vf[3];
#pragma unroll
        for (int j = 0; j < 3; ++j) vf[j] = *(const float4*)(x + gbase + 4 * j);

        for (int t0 = 0; t0 < wavemax; t0 += TS) {
            // stage tile: 4 cells/lane, one ds_write_b128 per cell
            float f12[12] = {vf[0].x, vf[0].y, vf[0].z, vf[0].w,
                             vf[1].x, vf[1].y, vf[1].z, vf[1].w,
                             vf[2].x, vf[2].y, vf[2].z, vf[2].w};
#pragma unroll
            for (int jj = 0; jj < 4; ++jj) {
                float a0 = f12[3 * jj], a1 = f12[3 * jj + 1], a2 = f12[3 * jj + 2];
                unsigned int w0 = cvtpk(a0, a1);          // [xh0|xh1]
                unsigned int w1 = cvtpk(a2, 1.0f);        // [xh2|bias]
                float r0 = a0 - __uint_as_float(w0 << 16);
                float r1 = a1 - __uint_as_float(w0 & 0xFFFF0000u);
                float r2 = a2 - __uint_as_float(w1 << 16);
                unsigned int w2 = cvtpk(r0, r1);          // [xl0|xl1]
                unsigned int w3 = cvtpk(r2, 0.0f);        // [xl2|0]
                int t = tq * 4 + jj;
                *(u4a*)&xbf[wid][(t * SB + ssl) * XSTR] = make_uint4(w0, w1, w2, w3);
            }
            // prefetch next tile
            if (t0 + TS < wavemax) {
                size_t off = (size_t)(t0 + TS) * NF;
#pragma unroll
                for (int j = 0; j < 3; ++j)
                    vf[j] = *(const float4*)(x + gbase + off + 4 * j);
            }

            int kmax = wavemax - t0; if (kmax > TS) kmax = TS;
            int ku = wavemin - t0;
            ku = ku < 0 ? 0 : (ku > kmax ? kmax : ku);
            int k = 0;
            for (; k < ku; ++k)   LSTM_STEP(k, false)   // all lanes active
            for (; k < kmax; ++k) LSTM_STEP(k, true)    // masked tail
        }
    }

    // epilogue: summary linear. Lane (n16,kg) -> outputs o = 4*kg..4*kg+3
    float hl[NH];
#pragma unroll
    for (int u = 0; u < NH; ++u) hl[u] = bf2f(hbf[wid][n16 * HSTR + u]);
    float4 res;
    if (mylen > 0) {
        float r4[4];
#pragma unroll
        for (int j = 0; j < 4; ++j) {
            int o = 4 * kg + j;
            float aa = b_lin[o];
#pragma unroll
            for (int kk = 0; kk < NH; ++kk) aa += w_lin[o * NH + kk] * hl[kk];
            r4[j] = fsig(aa);
        }
        res = make_float4(r4[0], r4[1], r4[2], r4[3]);
    } else {
        res = make_float4(0.f, 0.f, 0.f, 0.f);
    }
    *(float4*)(feat + (size_t)nown * NO + 4 * kg) = res;
}

// ---------------- conv stack + fc head: 2 batch rows per block ----
// LDS arena with lifetime overlay ({sf|y1} peak 18.2 KB -> 8 blocks/CU).
// Conv accumulators packed as f32x2 pairs over oc -> v_pk_fma_f32 (R7 idiom).
// Wave q handles oc q*8..q*8+7; conv2/conv3 put batch 0 on lanes 0..31 and
// batch 1 on lanes 32..63.  fc1/fc2 run on waves 0 and 1.
// Block 0 clears the sort barrier flags for the next iteration.
__global__ __launch_bounds__(256) void head_kernel(
    const float* __restrict__ feat,  // [NB][NL][16]
    unsigned int* __restrict__ flags,
    const float* __restrict__ c1w, const float* __restrict__ c1b,
    const float* __restrict__ c2w, const float* __restrict__ c2b,
    const float* __restrict__ c3w, const float* __restrict__ c3b,
    const float* __restrict__ f1w, const float* __restrict__ f1b,
    const float* __restrict__ f2w, const float* __restrict__ f2b,
    float* __restrict__ out)         // [NB][4]
{
    const int b0  = blockIdx.x * 2;
    const int tid = threadIdx.x;
    const int p   = tid & 63;
    const int q   = __builtin_amdgcn_readfirstlane(tid >> 6);  // oc-octet 0..3
    const int half = p >> 5;         // batch within wave (conv2/3)
    const int pp   = p & 31;         // position within half

    if (blockIdx.x == 0 && tid < 64) flags[tid] = 0u;  // reset sort barrier

    // arena (floats): [0,1600) sf -> later y2 [0,1408) + r1 [1440,1472)
    //                 [1600,4544) y1 -> later y3 [1600,2816)
    __shared__ __align__(16) float arena[4544];        // 18176 B
    float* sfp = arena;              // sf[bb][o*50+l]   = sfp[bb*800 + ...]
    float* y1p = arena + 1600;       // y1[bb][oc*46+p]  = y1p[bb*1472 + ...]
    float* y2p = arena;              // y2[bb][oc*22+pp] = y2p[bb*704 + ...]
    float* y3p = arena + 1600;       // y3[bb][oc*19+pp] = y3p[bb*608 + ...]
    float* r1p = arena + 1440;       // r1[bb][u]        = r1p[bb*16 + u]

    for (int i = tid; i < 2 * NL * NO; i += 256) {
        int bb = (i >= NL * NO) ? 1 : 0;
        int j = i - bb * (NL * NO);
        int l = j >> 4, o = j & 15;
        sfp[bb * 800 + o * 50 + l] = feat[(size_t)(b0 + bb) * (NL * NO) + j];
    }
    __syncthreads();

    const int oc0 = q * 8;

    // conv1: 16ch k5 s1 -> 32ch x 46, relu. Two passes (one per batch);
    // weights are wave-uniform and hoisted across passes.
#pragma unroll
    for (int bb = 0; bb < 2; ++bb) {
        if (p < 46) {
            f32x2 acc[4];
#pragma unroll
            for (int j = 0; j < 4; ++j)
                acc[j] = (f32x2){c1b[oc0 + 2*j], c1b[oc0 + 2*j + 1]};
#pragma unroll
            for (int ic = 0; ic < 16; ++ic) {
#pragma unroll
                for (int tap = 0; tap < 5; ++tap) {
                    float fv = sfp[bb * 800 + ic * 50 + p + tap];
                    f32x2 fv2 = {fv, fv};
#pragma unroll
                    for (int j = 0; j < 4; ++j) {
                        f32x2 w2 = {c1w[((oc0 + 2*j)     * 16 + ic) * 5 + tap],
                                    c1w[((oc0 + 2*j + 1) * 16 + ic) * 5 + tap]};
                        acc[j] += w2 * fv2;
                    }
                }
            }
#pragma unroll
            for (int j = 0; j < 4; ++j) {
                y1p[bb * 1472 + (oc0 + 2*j)     * 46 + p] = fmaxf(acc[j].x, 0.0f);
                y1p[bb * 1472 + (oc0 + 2*j + 1) * 46 + p] = fmaxf(acc[j].y, 0.0f);
            }
        }
    }
    __syncthreads();   // sf dead; y2 may overwrite it

    // conv2: 32ch k4 s2 -> 32ch x 22, relu. half = batch, pp = position.
    if (pp < 22) {
        f32x2 acc[4];
#pragma unroll
        for (int j = 0; j < 4; ++j)
            acc[j] = (f32x2){c2b[oc0 + 2*j], c2b[oc0 + 2*j + 1]};
#pragma unroll
        for (int ic = 0; ic < 32; ++ic) {
#pragma unroll
            for (int tap = 0; tap < 4; ++tap) {
                float fv = y1p[half * 1472 + ic * 46 + 2 * pp + tap];
                f32x2 fv2 = {fv, fv};
#pragma unroll
                for (int j = 0; j < 4; ++j) {
                    f32x2 w2 = {c2w[((oc0 + 2*j)     * 32 + ic) * 4 + tap],
                                c2w[((oc0 + 2*j + 1) * 32 + ic) * 4 + tap]};
                    acc[j] += w2 * fv2;
                }
            }
        }
#pragma unroll
        for (int j = 0; j < 4; ++j) {
            y2p[half * 704 + (oc0 + 2*j)     * 22 + pp] = fmaxf(acc[j].x, 0.0f);
            y2p[half * 704 + (oc0 + 2*j + 1) * 22 + pp] = fmaxf(acc[j].y, 0.0f);
        }
    }
    __syncthreads();   // y1 dead; y3 may overwrite it

    // conv3: 32ch k4 s1 -> 32ch x 19, relu
    if (pp < 19) {
        f32x2 acc[4];
#pragma unroll
        for (int j = 0; j < 4; ++j)
            acc[j] = (f32x2){c3b[oc0 + 2*j], c3b[oc0 + 2*j + 1]};
#pragma unroll
        for (int ic = 0; ic < 32; ++ic) {
#pragma unroll
            for (int tap = 0; tap < 4; ++tap) {
                float fv = y2p[half * 704 + ic * 22 + pp + tap];
                f32x2 fv2 = {fv, fv};
#pragma unroll
                for (int j = 0; j < 4; ++j) {
                    f32x2 w2 = {c3w[((oc0 + 2*j)     * 32 + ic) * 4 + tap],
                                c3w[((oc0 + 2*j + 1) * 32 + ic) * 4 + tap]};
                    acc[j] += w2 * fv2;
                }
            }
        }
#pragma unroll
        for (int j = 0; j < 4; ++j) {
            y3p[half * 608 + (oc0 + 2*j)     * 19 + pp] = fmaxf(acc[j].x, 0.0f);
            y3p[half * 608 + (oc0 + 2*j + 1) * 19 + pp] = fmaxf(acc[j].y, 0.0f);
        }
    }
    __syncthreads();

    // fc1: 608 -> 16, relu. Wave 0 -> batch 0, wave 1 -> batch 1.
    // float4 weight loads + same-address (broadcast) float4 LDS reads.
    if (q < 2) {
        int u  = p & 15;
        int qq = p >> 4;
        const float4* wv = (const float4*)(f1w + u * 608 + qq * 152);
        const float4* yv = (const float4*)(y3p + q * 608 + qq * 152);
        float acc = 0.0f;
#pragma unroll 2
        for (int k = 0; k < 38; ++k) {
            float4 a = wv[k], bv = yv[k];
            acc += a.x * bv.x + a.y * bv.y + a.z * bv.z + a.w * bv.w;
        }
        acc += __shfl_xor(acc, 16);
        acc += __shfl_xor(acc, 32);
        if (p < 16) r1p[q * 16 + p] = fmaxf(acc + f1b[p], 0.0f);
    }
    __syncthreads();

    // fc2: 16 -> 4. Wave 0 -> batch 0, wave 1 -> batch 1.
    if (q < 2 && p < 4) {
        float s = f2b[p];
#pragma unroll
        for (int k = 0; k < 16; ++k) s += f2w[p * 16 + k] * r1p[q * 16 + k];
        out[(size_t)(b0 + q) * 4 + p] = s;
    }
}

extern "C" void kernel_launch(void* const* d_in, const int* in_sizes, int n_in,
                              void* d_out, int out_size, void* d_ws, size_t ws_size,
                              hipStream_t stream)
{
    const float* x     = (const float*)d_in[0];
    const int*  lengths= (const int*)  d_in[1];
    const float* w_ih  = (const float*)d_in[2];
    const float* w_hh  = (const float*)d_in[3];
    const float* b_ih  = (const float*)d_in[4];
    const float* b_hh  = (const float*)d_in[5];
    const float* w_lin = (const float*)d_in[6];
    const float* b_lin = (const float*)d_in[7];
    const float* c1w   = (const float*)d_in[8];
    const float* c1b   = (const float*)d_in[9];
    const float* c2w   = (const float*)d_in[10];
    const float* c2b   = (const float*)d_in[11];
    const float* c3w   = (const float*)d_in[12];
    const float* c3b   = (const float*)d_in[13];
    const float* f1w   = (const float*)d_in[14];
    const float* f1b   = (const float*)d_in[15];
    const float* f2w   = (const float*)d_in[16];
    const float* f2b   = (const float*)d_in[17];
    float* out = (float*)d_out;

    // workspace layout (~14.8 MB), all segments 16B-aligned
    char* ws      = (char*)d_ws;
    float* feat   = (float*)ws;                       // NN*16 floats
    int*   order  = (int*)(feat + (size_t)NN * NO);   // NN
    int*   len_s  = order + NN;                       // NN
    int*   bhist  = len_s + NN;                       // 64*64
    unsigned int* flags = (unsigned int*)(bhist + 64 * 64); // 64
    unsigned int* wfrag = flags + 64;                 // 2560

    sort_kernel <<<65, 256, 0, stream>>>(lengths, bhist, flags, order, len_s,
                                         w_hh, b_ih, b_hh, w_ih, wfrag);
    lstm_kernel <<<NN / (SB * WPB), 128, 0, stream>>>(x, len_s, order, wfrag,
                                                      w_lin, b_lin, feat);
    head_kernel <<<NB / 2, 256, 0, stream>>>(feat, flags,
                                             c1w, c1b, c2w, c2b, c3w, c3b,
                                             f1w, f1b, f2w, f2b, out);
}